// Round 1
// baseline (54.358 us; speedup 1.0000x reference)
//
#include <hip/hip_runtime.h>

#define CHUNK_ROWS 256
#define TPB 256
#define ROW_F 25
#define CHUNK_F (CHUNK_ROWS * ROW_F)   // 6400 floats per array per chunk
#define CHUNK_F4 (CHUNK_F / 4)         // 1600 float4

// stable rank of 4 values (tie-break: lower index first) — matches jnp stable argsort
__device__ __forceinline__ void rank4(const float v[4], int r[4]) {
#pragma unroll
    for (int i = 0; i < 4; ++i) {
        int rk = 0;
#pragma unroll
        for (int j = 0; j < 4; ++j)
            rk += (v[j] < v[i] || (v[j] == v[i] && j < i)) ? 1 : 0;
        r[i] = rk;
    }
}

__device__ __forceinline__ void judge_group(const float* __restrict__ p,
                                            const float* __restrict__ t,
                                            int& calc, int& acc) {
    const float ERRv = 0.09f;   // 3 * 0.03
    const float GAPv = 0.03f;   // 3 * 0.01
    float p0 = p[0], p1 = p[1], p2 = p[2], p3 = p[3];
    float t0 = t[0], t1 = t[1], t2 = t[2], t3 = t[3];

    // out = 3 * softmax(p)
    float m  = fmaxf(fmaxf(p0, p1), fmaxf(p2, p3));
    float e0 = __expf(p0 - m), e1 = __expf(p1 - m);
    float e2 = __expf(p2 - m), e3 = __expf(p3 - m);
    float inv = 3.0f / (e0 + e1 + e2 + e3);
    float o0 = e0 * inv, o1 = e1 * inv, o2 = e2 * inv, o3 = e3 * inv;

    bool within = fabsf(o0 - t0) <= ERRv && fabsf(o1 - t1) <= ERRv &&
                  fabsf(o2 - t2) <= ERRv && fabsf(o3 - t3) <= ERRv;

    // sorted target values (ascending), need st0..st2
    float l01 = fminf(t0, t1), h01 = fmaxf(t0, t1);
    float l23 = fminf(t2, t3), h23 = fmaxf(t2, t3);
    float st0 = fminf(l01, l23), mlo = fmaxf(l01, l23);
    float mhi = fminf(h01, h23);
    float st1 = fminf(mlo, mhi), st2 = fmaxf(mlo, mhi);
    float d1 = st1 - st0;   // |st0 - st1|, nonneg by construction
    float d2 = st2 - st1;   // |st2 - st1|

    float ov[4] = {o0, o1, o2, o3};
    float tv[4] = {t0, t1, t2, t3};
    int ro[4], rt[4];
    rank4(ov, ro);   // rank_out: position of each original element
    rank4(tv, rt);   // rank_tar

    bool jump = within && (
        (d1 < GAPv && d2 < GAPv) ||
        (d1 < GAPv && ro[2] == rt[2]) ||
        (d2 < GAPv && ro[0] == rt[0]));

    int nz = (t0 == 0.0f) + (t1 == 0.0f) + (t2 == 0.0f) + (t3 == 0.0f);
    bool match_all = (ro[0] == rt[0]) && (ro[1] == rt[1]) &&
                     (ro[2] == rt[2]) && (ro[3] == rt[3]);

    // tag[k] = index whose rank is k
    int tago2 = 0, tago3 = 0, tagt2 = 0, tagt3 = 0;
#pragma unroll
    for (int i = 0; i < 4; ++i) {
        if (ro[i] == 2) tago2 = i;
        if (ro[i] == 3) tago3 = i;
        if (rt[i] == 2) tagt2 = i;
        if (rt[i] == 3) tagt3 = i;
    }

    bool c_lt2 = !jump && (nz < 2);
    bool c_eq2 = !jump && (nz == 2) && (tago2 == tagt2) && (tago3 == tagt3);
    bool c_eq3 = !jump && (nz == 3) && (ro[3] == 3);   // tagout[3] == 3

    calc += (jump || c_lt2 || c_eq2 || c_eq3) ? 1 : 0;
    acc  += (jump || (c_lt2 && match_all) || c_eq2 || c_eq3) ? 1 : 0;
}

__global__ __launch_bounds__(TPB)
void recall_main_kernel(const float* __restrict__ pre,
                        const float* __restrict__ tar,
                        float* __restrict__ partial,
                        int B, int nchunks) {
    __shared__ float s_pre[CHUNK_F];
    __shared__ float s_tar[CHUNK_F];
    __shared__ float s_red[8];

    const int t = threadIdx.x;
    const int total  = B * ROW_F;
    const int total4 = total >> 2;

    const float4* pre4 = (const float4*)pre;
    const float4* tar4 = (const float4*)tar;
    float4* sp4 = (float4*)s_pre;
    float4* st4 = (float4*)s_tar;

    float csum = 0.0f, vsum = 0.0f;

    for (int chunk = blockIdx.x; chunk < nchunks; chunk += gridDim.x) {
        __syncthreads();   // previous iteration's LDS reads done before overwrite

        const int base  = chunk * CHUNK_F;    // float index, multiple of 4
        const int base4 = chunk * CHUNK_F4;

        // coalesced float4 staging (1600 float4 per array)
#pragma unroll
        for (int k = 0; k < 7; ++k) {
            int li = t + k * TPB;
            if (li < CHUNK_F4) {
                int gi = base4 + li;
                if (gi < total4) {
                    sp4[li] = pre4[gi];
                    st4[li] = tar4[gi];
                }
            }
        }
        // scalar tail (only if total % 4 != 0 and this chunk owns it)
        if (base + CHUNK_F > (total4 << 2)) {
            for (int li = t; li < CHUNK_F; li += TPB) {
                int gi = base + li;
                if (gi >= (total4 << 2) && gi < total) {
                    s_pre[li] = pre[gi];
                    s_tar[li] = tar[gi];
                }
            }
        }
        __syncthreads();

        int row = chunk * CHUNK_ROWS + t;
        if (row < B) {
            const float* rp = &s_pre[t * ROW_F];
            const float* rt = &s_tar[t * ROW_F];
            int calc = 0, acc = 0;
#pragma unroll
            for (int g = 0; g < 6; ++g)
                judge_group(rp + g * 4, rt + g * 4, calc, acc);
            if (calc > 0) {
                csum += (float)acc / (float)calc;
                vsum += 1.0f;
            }
        }
    }

    // block reduction (deterministic)
#pragma unroll
    for (int off = 32; off > 0; off >>= 1) {
        csum += __shfl_down(csum, off);
        vsum += __shfl_down(vsum, off);
    }
    int wave = t >> 6;
    if ((t & 63) == 0) { s_red[wave] = csum; s_red[4 + wave] = vsum; }
    __syncthreads();
    if (t == 0) {
        float c = s_red[0] + s_red[1] + s_red[2] + s_red[3];
        float v = s_red[4] + s_red[5] + s_red[6] + s_red[7];
        partial[2 * blockIdx.x]     = c;
        partial[2 * blockIdx.x + 1] = v;
    }
}

__global__ __launch_bounds__(TPB)
void recall_finalize_kernel(const float* __restrict__ partial, int n,
                            float* __restrict__ out) {
    __shared__ float s_red[8];
    float c = 0.0f, v = 0.0f;
    for (int i = threadIdx.x; i < n; i += TPB) {
        c += partial[2 * i];
        v += partial[2 * i + 1];
    }
#pragma unroll
    for (int off = 32; off > 0; off >>= 1) {
        c += __shfl_down(c, off);
        v += __shfl_down(v, off);
    }
    int wave = threadIdx.x >> 6;
    if ((threadIdx.x & 63) == 0) { s_red[wave] = c; s_red[4 + wave] = v; }
    __syncthreads();
    if (threadIdx.x == 0) {
        float cs = s_red[0] + s_red[1] + s_red[2] + s_red[3];
        float vs = s_red[4] + s_red[5] + s_red[6] + s_red[7];
        out[0] = (vs > 0.0f) ? (cs / vs) : 0.0f;
    }
}

extern "C" void kernel_launch(void* const* d_in, const int* in_sizes, int n_in,
                              void* d_out, int out_size, void* d_ws, size_t ws_size,
                              hipStream_t stream) {
    const float* pre = (const float*)d_in[0];
    const float* tar = (const float*)d_in[1];
    float* out = (float*)d_out;
    float* partial = (float*)d_ws;

    int B = in_sizes[0] / ROW_F;
    int nchunks = (B + CHUNK_ROWS - 1) / CHUNK_ROWS;

    int grid = nchunks < 2048 ? nchunks : 2048;   // partials: grid*8 B <= 16 KB in d_ws
    if (grid < 1) grid = 1;

    recall_main_kernel<<<grid, TPB, 0, stream>>>(pre, tar, partial, B, nchunks);
    recall_finalize_kernel<<<1, TPB, 0, stream>>>(partial, grid, out);
}